// Round 2
// baseline (112.323 us; speedup 1.0000x reference)
//
#include <hip/hip_runtime.h>

// loss = (dot(x[0:half], x[half:2*half]) / rows + 1) / 2, rows = half/1024.
// Row-major layout makes sum_i dot(real_i, fake_i) a flat dot of the two halves.
//
// Single fused kernel: grid-wide partials + last-block finalize (deterministic:
// the final summation order over partials[0..GRID-1] is fixed regardless of
// which block arrives last). Counter zeroed per-call via 4-byte memset node.

constexpr int BLOCK = 256;
constexpr int GRID  = 2048;   // 256 CUs x 8 blocks -> full occupancy

__global__ __launch_bounds__(BLOCK) void dot_fused_kernel(
    const float4* __restrict__ a, const float4* __restrict__ b,
    float* __restrict__ partials, unsigned int* __restrict__ counter,
    float* __restrict__ out, long n4, float inv_count)
{
    const long tid    = (long)blockIdx.x * BLOCK + threadIdx.x;
    const long stride = (long)GRID * BLOCK;

    // 4x unrolled main loop, 4 independent accumulators -> 8 loads in flight
    float acc0 = 0.f, acc1 = 0.f, acc2 = 0.f, acc3 = 0.f;
    long i = tid;
    for (; i + 3 * stride < n4; i += 4 * stride) {
        float4 x0 = a[i];              float4 y0 = b[i];
        float4 x1 = a[i + stride];     float4 y1 = b[i + stride];
        float4 x2 = a[i + 2 * stride]; float4 y2 = b[i + 2 * stride];
        float4 x3 = a[i + 3 * stride]; float4 y3 = b[i + 3 * stride];
        acc0 += x0.x * y0.x + x0.y * y0.y + x0.z * y0.z + x0.w * y0.w;
        acc1 += x1.x * y1.x + x1.y * y1.y + x1.z * y1.z + x1.w * y1.w;
        acc2 += x2.x * y2.x + x2.y * y2.y + x2.z * y2.z + x2.w * y2.w;
        acc3 += x3.x * y3.x + x3.y * y3.y + x3.z * y3.z + x3.w * y3.w;
    }
    for (; i < n4; i += stride) {      // tail (unused for the bench shape)
        float4 x = a[i]; float4 y = b[i];
        acc0 += x.x * y.x + x.y * y.y + x.z * y.z + x.w * y.w;
    }
    float acc = (acc0 + acc1) + (acc2 + acc3);

    // wave-64 butterfly, then cross-wave via LDS
    #pragma unroll
    for (int off = 32; off > 0; off >>= 1)
        acc += __shfl_down(acc, off, 64);

    __shared__ float s[BLOCK / 64];
    __shared__ bool  is_last;
    const int lane = threadIdx.x & 63;
    const int wave = threadIdx.x >> 6;
    if (lane == 0) s[wave] = acc;
    __syncthreads();

    if (threadIdx.x == 0) {
        partials[blockIdx.x] = s[0] + s[1] + s[2] + s[3];
        __threadfence();                       // publish partial (device scope)
        unsigned int prev = atomicAdd(counter, 1u);
        is_last = (prev == (unsigned int)(GRID - 1));
    }
    __syncthreads();
    if (!is_last) return;

    __threadfence();                           // acquire all partials
    float f = 0.f;
    #pragma unroll
    for (int k = 0; k < GRID / BLOCK; ++k)
        f += partials[k * BLOCK + threadIdx.x];
    #pragma unroll
    for (int off = 32; off > 0; off >>= 1)
        f += __shfl_down(f, off, 64);
    if (lane == 0) s[wave] = f;
    __syncthreads();
    if (threadIdx.x == 0)
        out[0] = ((s[0] + s[1] + s[2] + s[3]) * inv_count + 1.0f) * 0.5f;
}

extern "C" void kernel_launch(void* const* d_in, const int* in_sizes, int n_in,
                              void* d_out, int out_size, void* d_ws, size_t ws_size,
                              hipStream_t stream) {
    const float* x = (const float*)d_in[0];
    long n    = (long)in_sizes[0];   // 65536 * 1024
    long half = n / 2;
    long n4   = half / 4;
    long rows = half / 1024;

    const float4* a = (const float4*)x;
    const float4* b = (const float4*)(x + half);

    float* partials        = (float*)d_ws;
    unsigned int* counter  = (unsigned int*)((char*)d_ws + GRID * sizeof(float));

    // counter must be 0 at kernel start every call (ws is poisoned, not reset)
    hipMemsetAsync(counter, 0, sizeof(unsigned int), stream);

    dot_fused_kernel<<<GRID, BLOCK, 0, stream>>>(
        a, b, partials, counter, (float*)d_out, n4, 1.0f / (float)rows);
}

// Round 3
// 46.779 us; speedup vs baseline: 2.4011x; 2.4011x over previous
//
#include <hip/hip_runtime.h>

// loss = (dot(x[0:half], x[half:n]) / rows + 1) / 2, rows = half/1024.
// Row-major => sum_i dot(real_i, fake_i) is a flat dot of the two halves.
//
// Two kernels (R2 lesson: single-dispatch cross-XCD fencing costs ~150us;
// a graph-captured second launch costs ~4us). Main kernel: 4x unrolled
// grid-stride, 4 independent accumulators -> 8 dwordx4 loads in flight.

constexpr int BLOCK = 256;
constexpr int GRID  = 2048;   // 256 CUs x 8 blocks co-resident

__global__ __launch_bounds__(BLOCK) void dot_partial_kernel(
    const float4* __restrict__ a, const float4* __restrict__ b,
    float* __restrict__ partials, long n4)
{
    const long tid    = (long)blockIdx.x * BLOCK + threadIdx.x;
    const long stride = (long)GRID * BLOCK;

    float acc0 = 0.f, acc1 = 0.f, acc2 = 0.f, acc3 = 0.f;
    long i = tid;
    for (; i + 3 * stride < n4; i += 4 * stride) {
        float4 x0 = a[i];              float4 y0 = b[i];
        float4 x1 = a[i + stride];     float4 y1 = b[i + stride];
        float4 x2 = a[i + 2 * stride]; float4 y2 = b[i + 2 * stride];
        float4 x3 = a[i + 3 * stride]; float4 y3 = b[i + 3 * stride];
        acc0 += x0.x * y0.x + x0.y * y0.y + x0.z * y0.z + x0.w * y0.w;
        acc1 += x1.x * y1.x + x1.y * y1.y + x1.z * y1.z + x1.w * y1.w;
        acc2 += x2.x * y2.x + x2.y * y2.y + x2.z * y2.z + x2.w * y2.w;
        acc3 += x3.x * y3.x + x3.y * y3.y + x3.z * y3.z + x3.w * y3.w;
    }
    for (; i < n4; i += stride) {   // tail (empty at the bench shape)
        float4 x = a[i]; float4 y = b[i];
        acc0 += x.x * y.x + x.y * y.y + x.z * y.z + x.w * y.w;
    }
    float acc = (acc0 + acc1) + (acc2 + acc3);

    #pragma unroll
    for (int off = 32; off > 0; off >>= 1)
        acc += __shfl_down(acc, off, 64);

    __shared__ float s[BLOCK / 64];
    const int lane = threadIdx.x & 63;
    const int wave = threadIdx.x >> 6;
    if (lane == 0) s[wave] = acc;
    __syncthreads();
    if (threadIdx.x == 0)
        partials[blockIdx.x] = (s[0] + s[1]) + (s[2] + s[3]);
}

__global__ __launch_bounds__(BLOCK) void finalize_kernel(
    const float4* __restrict__ partials4, float* __restrict__ out,
    float inv_count)
{
    // GRID/4 = 512 float4; 256 threads read 2 each
    float4 p0 = partials4[threadIdx.x];
    float4 p1 = partials4[threadIdx.x + BLOCK];
    float acc = (p0.x + p0.y + p0.z + p0.w) + (p1.x + p1.y + p1.z + p1.w);

    #pragma unroll
    for (int off = 32; off > 0; off >>= 1)
        acc += __shfl_down(acc, off, 64);

    __shared__ float s[BLOCK / 64];
    const int lane = threadIdx.x & 63;
    const int wave = threadIdx.x >> 6;
    if (lane == 0) s[wave] = acc;
    __syncthreads();
    if (threadIdx.x == 0)
        out[0] = (((s[0] + s[1]) + (s[2] + s[3])) * inv_count + 1.0f) * 0.5f;
}

extern "C" void kernel_launch(void* const* d_in, const int* in_sizes, int n_in,
                              void* d_out, int out_size, void* d_ws, size_t ws_size,
                              hipStream_t stream) {
    const float* x = (const float*)d_in[0];
    long n    = (long)in_sizes[0];   // 65536 * 1024
    long half = n / 2;
    long n4   = half / 4;
    long rows = half / 1024;

    const float4* a = (const float4*)x;
    const float4* b = (const float4*)(x + half);
    float* partials = (float*)d_ws;

    dot_partial_kernel<<<GRID, BLOCK, 0, stream>>>(a, b, partials, n4);
    finalize_kernel<<<1, BLOCK, 0, stream>>>((const float4*)partials,
                                             (float*)d_out,
                                             1.0f / (float)rows);
}